// Round 15
// baseline (323.962 us; speedup 1.0000x reference)
//
#include <hip/hip_runtime.h>
#include <hip/hip_bf16.h>

typedef __attribute__((ext_vector_type(4))) float f32x4;
typedef __attribute__((ext_vector_type(8))) short bf16x8;
typedef __attribute__((ext_vector_type(8))) unsigned short u16x8;
typedef __attribute__((ext_vector_type(4))) unsigned short u16x4;

#define NN 8192
#define SK 8
#define KSL (NN / SK)      // 1024 k per WG
#define NT (KSL / 64)      // 16 tiles of 64 k

__device__ __forceinline__ unsigned short f2bf(float f) {
    unsigned int u = __float_as_uint(f);
    u += 0x7fffu + ((u >> 16) & 1u);
    return (unsigned short)(u >> 16);
}

__device__ __forceinline__ void gload16(const void* g, void* l) {
    __builtin_amdgcn_global_load_lds(
        (const __attribute__((address_space(1))) unsigned int*)g,
        (__attribute__((address_space(3))) unsigned int*)l, 16, 0, 0);
}

__global__ __launch_bounds__(256) void prep_v(const float* __restrict__ La,
        const float* __restrict__ ve, const float* __restrict__ ve2,
        float* __restrict__ V1, float* __restrict__ V2) {
    int i = blockIdx.x * 256 + threadIdx.x;
    float la = La[i];
    V1[i] = powf(la, ve[0]);
    float b = 2.0f * (la - 1e-8f) - 1.0f;
    V2[i] = powf(b * b + 1.0f, ve2[0]);
}

// ---------------------------------------------------------------------------
// FB frag layout (small matrix M[8192][64]):
//   FB[((b*4+nf)*64 + l)*8 + s] = M[32b + 8(l>>4) + s][16nf + (l&15)]
//
// spec_f32<EMIT>: t-mode, f32 U. C'[m][n] = sum_k M[k][m]*U[k][n];
// out Pt[sk][64][NN]. 64-k 16KB tiles via global_load_lds (dbuf,
// source-XOR-swizzle, LDS linear). EMIT=1: echo bf16(U) row-major to Uemit.
// ---------------------------------------------------------------------------
template<int EMIT>
__global__ __launch_bounds__(256, 4) void spec_f32(const float* __restrict__ U,
        const unsigned short* __restrict__ FB, float* __restrict__ Pout,
        unsigned short* __restrict__ Uemit) {
    __shared__ float tile[2][4096];          // 2 x 16 KB
    const int tid = threadIdx.x;
    const int w = tid >> 6, l = tid & 63;
    const int lm = l & 15, g = l >> 4;
    const int x0 = blockIdx.x * 64;          // col-block
    const int kbase = blockIdx.y * KSL;
    const int kb0 = kbase >> 5;
    const unsigned short* fbL = FB + (size_t)l * 8;

    f32x4 acc[4];
#pragma unroll
    for (int f = 0; f < 4; ++f) acc[f] = (f32x4)0.f;

#define STAGE(B, CT)                                                           \
    do {                                                                       \
        _Pragma("unroll")                                                      \
        for (int q_ = 0; q_ < 4; ++q_) {                                       \
            const int cc_ = 4 * w + q_;                                        \
            const int row_ = 4 * cc_ + (l >> 4);                               \
            const int su_ = (l & 15) ^ (row_ & 7);                             \
            const float* gp_ = U +                                             \
                (size_t)(kbase + (CT) * 64 + row_) * NN + x0 + su_ * 4;        \
            gload16(gp_, &tile[B][cc_ * 256]);                                 \
        }                                                                      \
    } while (0)

#define LOADFB(R, CT)                                                          \
    do {                                                                       \
        _Pragma("unroll")                                                      \
        for (int sp_ = 0; sp_ < 2; ++sp_)                                      \
            _Pragma("unroll")                                                  \
            for (int f_ = 0; f_ < 4; ++f_)                                     \
                R[sp_][f_] = *(const bf16x8*)(fbL +                            \
                    ((size_t)((kb0 + 2 * (CT) + sp_) * 4 + f_)) * 512);        \
    } while (0)

#define COMPUTE(B, FBR)                                                        \
    do {                                                                       \
        _Pragma("unroll")                                                      \
        for (int sp_ = 0; sp_ < 2; ++sp_) {                                    \
            bf16x8 bfr_;                                                       \
            _Pragma("unroll")                                                  \
            for (int s_ = 0; s_ < 8; ++s_)                                     \
                bfr_[s_] = (short)f2bf(tile[B][                                \
                    (32 * sp_ + 8 * g + s_) * 64 +                             \
                    (((4 * w + (lm >> 2)) ^ s_) << 2) + (lm & 3)]);            \
            _Pragma("unroll")                                                  \
            for (int f_ = 0; f_ < 4; ++f_)                                     \
                acc[f_] = __builtin_amdgcn_mfma_f32_16x16x32_bf16(             \
                    FBR[sp_][f_], bfr_, acc[f_], 0, 0, 0);                     \
        }                                                                      \
    } while (0)

#define ECHO(B, CT)                                                            \
    do {                                                                       \
        if (EMIT) {                                                            \
            _Pragma("unroll")                                                  \
            for (int q_ = 0; q_ < 4; ++q_) {                                   \
                const int cc_ = 4 * w + q_;                                    \
                const int row_ = 4 * cc_ + (l >> 4);                           \
                const int su_ = (l & 15) ^ (row_ & 7);                         \
                f32x4 v_ = *(const f32x4*)&tile[B][cc_ * 256 + l * 4];         \
                u16x4 h_;                                                      \
                _Pragma("unroll")                                              \
                for (int q2_ = 0; q2_ < 4; ++q2_) h_[q2_] = f2bf(v_[q2_]);     \
                *(u16x4*)(Uemit +                                              \
                    (size_t)(kbase + (CT) * 64 + row_) * NN + x0 + su_ * 4)    \
                    = h_;                                                      \
            }                                                                  \
        }                                                                      \
    } while (0)

    bf16x8 fbA[2][4], fbB[2][4];
    LOADFB(fbA, 0);
    STAGE(0, 0);
    __syncthreads();
#pragma unroll 1
    for (int c = 0; c < NT; c += 2) {
        if (c + 1 < NT) { LOADFB(fbB, c + 1); STAGE(1, c + 1); }
        COMPUTE(0, fbA);
        ECHO(0, c);
        __syncthreads();
        if (c + 2 < NT) { LOADFB(fbA, c + 2); STAGE(0, c + 2); }
        COMPUTE(1, fbB);
        ECHO(1, c + 1);
        __syncthreads();
    }
#undef STAGE
#undef LOADFB
#undef COMPUTE
#undef ECHO

    float* Pp = Pout + (size_t)blockIdx.y * 64 * NN;
#pragma unroll
    for (int f = 0; f < 4; ++f)
#pragma unroll
        for (int r = 0; r < 4; ++r)
            Pp[(size_t)(16 * f + 4 * g + r) * NN + x0 + 16 * w + lm] = acc[f][r];
}

// ---------------------------------------------------------------------------
// spec_nbf: n-mode, bf16 U, 64-k x 8KB tiles, FB PREFETCHED one tile ahead
// (ping-pong registers -> zero vmcnt waits inside compute; this is the fast
// r11 variant, NOT the inline-FB r12/r14 one).
//   C[i][j] = sum_k Ub[i][k]*S[k][j]; out P[sk][NN][64].
// ---------------------------------------------------------------------------
__global__ __launch_bounds__(256, 4) void spec_nbf(
        const unsigned short* __restrict__ Ub,
        const unsigned short* __restrict__ FB, float* __restrict__ Pout) {
    __shared__ unsigned short tile[2][4096];   // 2 x 8 KB
    const int tid = threadIdx.x;
    const int w = tid >> 6, l = tid & 63;
    const int lm = l & 15, g = l >> 4;
    const int x0 = blockIdx.x * 64;
    const int kbase = blockIdx.y * KSL;
    const int kb0 = kbase >> 5;
    const unsigned short* fbL = FB + (size_t)l * 8;

    f32x4 acc[4];
#pragma unroll
    for (int f = 0; f < 4; ++f) acc[f] = (f32x4)0.f;

#define STG(B, CT)                                                             \
    do {                                                                       \
        _Pragma("unroll")                                                      \
        for (int q_ = 0; q_ < 2; ++q_) {                                       \
            const int cc_ = 2 * w + q_;                                        \
            const int row_ = 8 * cc_ + (l >> 3);                               \
            const int su_ = (l & 7) ^ (row_ & 7);                              \
            const unsigned short* gp_ = Ub +                                   \
                (size_t)(x0 + row_) * NN + kbase + (CT) * 64 + su_ * 8;        \
            gload16(gp_, &tile[B][cc_ * 512]);                                 \
        }                                                                      \
    } while (0)

#define LOADFB(R, CT)                                                          \
    do {                                                                       \
        _Pragma("unroll")                                                      \
        for (int sp_ = 0; sp_ < 2; ++sp_)                                      \
            _Pragma("unroll")                                                  \
            for (int f_ = 0; f_ < 4; ++f_)                                     \
                R[sp_][f_] = *(const bf16x8*)(fbL +                            \
                    ((size_t)((kb0 + 2 * (CT) + sp_) * 4 + f_)) * 512);        \
    } while (0)

#define CMP(B, FBR)                                                            \
    do {                                                                       \
        _Pragma("unroll")                                                      \
        for (int sp_ = 0; sp_ < 2; ++sp_) {                                    \
            const unsigned short* rp_ = &tile[B][(16 * w + lm) * 64];          \
            bf16x8 afr_ = *(const bf16x8*)(rp_ +                               \
                (((4 * sp_ + g) ^ (lm & 7)) << 3));                            \
            _Pragma("unroll")                                                  \
            for (int f_ = 0; f_ < 4; ++f_)                                     \
                acc[f_] = __builtin_amdgcn_mfma_f32_16x16x32_bf16(             \
                    afr_, FBR[sp_][f_], acc[f_], 0, 0, 0);                     \
        }                                                                      \
    } while (0)

    bf16x8 fbA[2][4], fbB[2][4];
    LOADFB(fbA, 0);
    STG(0, 0);
    __syncthreads();
#pragma unroll 1
    for (int c = 0; c < NT; c += 2) {
        if (c + 1 < NT) { LOADFB(fbB, c + 1); STG(1, c + 1); }
        CMP(0, fbA);
        __syncthreads();
        if (c + 2 < NT) { LOADFB(fbA, c + 2); STG(0, c + 2); }
        CMP(1, fbB);
        __syncthreads();
    }
#undef STG
#undef LOADFB
#undef CMP

    float* Pp = Pout + (size_t)blockIdx.y * NN * 64;
#pragma unroll
    for (int f = 0; f < 4; ++f)
#pragma unroll
        for (int r = 0; r < 4; ++r)
            Pp[(size_t)(x0 + 16 * w + 4 * g + r) * 64 + f * 16 + lm] = acc[f][r];
}

// reduce2: FB = frag( colscale(V) * sum_sk Pt[sk][ch][i] ), Pt [SK][64][NN]
__global__ __launch_bounds__(256) void reduce2(const float* __restrict__ Pt,
        const float* __restrict__ V, unsigned short* __restrict__ FB) {
    int b = blockIdx.x;
    int t = threadIdx.x;
    int nf = t >> 6, l = t & 63, lm = l & 15, g = l >> 4;
    int ch = 16 * nf + lm;
    int ib = 32 * b + 8 * g;
    f32x4 s0 = (f32x4)0.f, s1 = (f32x4)0.f;
#pragma unroll
    for (int sk = 0; sk < SK; ++sk) {
        const float* p = Pt + (size_t)(sk * 64 + ch) * NN + ib;
        s0 += *(const f32x4*)p;
        s1 += *(const f32x4*)(p + 4);
    }
    f32x4 v0 = *(const f32x4*)(V + ib);
    f32x4 v1 = *(const f32x4*)(V + ib + 4);
    u16x8 o;
#pragma unroll
    for (int c = 0; c < 4; ++c) {
        o[c]     = f2bf(s0[c] * v0[c]);
        o[4 + c] = f2bf(s1[c] * v1[c]);
    }
    *(u16x8*)(FB + ((size_t)(b * 4 + nf) * 64 + l) * 8) = o;
}

// reduce_t: FB = frag( sum_sk M[sk][i][j] ), M [nsk][NN][64] row-major.
__global__ __launch_bounds__(256) void reduce_t(const float* __restrict__ M, int nsk,
        unsigned short* __restrict__ FB) {
    __shared__ float T[32][65];
    int b = blockIdx.x;
    int i0 = b * 32;
    int tid = threadIdx.x;
    int il = tid >> 3, jq = (tid & 7) * 8;
    f32x4 s0 = (f32x4)0.f, s1 = (f32x4)0.f;
    for (int k = 0; k < nsk; ++k) {
        const float* p = M + ((size_t)k * NN + i0 + il) * 64 + jq;
        s0 += *(const f32x4*)p;
        s1 += *(const f32x4*)(p + 4);
    }
#pragma unroll
    for (int c = 0; c < 4; ++c) {
        T[il][jq + c] = s0[c];
        T[il][jq + 4 + c] = s1[c];
    }
    __syncthreads();
    int nf = tid >> 6, l = tid & 63, g = l >> 4, lm = l & 15;
    u16x8 o;
#pragma unroll
    for (int s = 0; s < 8; ++s) o[s] = f2bf(T[8 * g + s][16 * nf + lm]);
    *(u16x8*)(FB + ((size_t)(b * 4 + nf) * 64 + l) * 8) = o;
}

// Z2 = sum of partials; hidden = Z2 @ Ww^T + Wb; also per-block BN partial sums.
__global__ __launch_bounds__(256) void reduce_linear(const float* __restrict__ P,
        const float* __restrict__ Ww, const float* __restrict__ Wb,
        float* __restrict__ hidden, float* __restrict__ bsum, float* __restrict__ bsq) {
    __shared__ float z[32][65];
    __shared__ float w[64][65];
    __shared__ float hl[32][65];
    int i0 = blockIdx.x * 32;
    int tid = threadIdx.x;
    for (int e = tid * 4; e < 4096; e += 1024) {
        f32x4 v = *(const f32x4*)(Ww + e);
        int h = e >> 6, c = e & 63;
#pragma unroll
        for (int q = 0; q < 4; ++q) w[h][c + q] = v[q];
    }
    int r = tid >> 3, c8 = (tid & 7) * 8;
    f32x4 a0 = (f32x4)0.f, a1 = (f32x4)0.f;
    for (int k = 0; k < SK; ++k) {
        const float* p = P + ((size_t)k * NN + i0 + r) * 64 + c8;
        a0 += *(const f32x4*)p;
        a1 += *(const f32x4*)(p + 4);
    }
#pragma unroll
    for (int q = 0; q < 4; ++q) { z[r][c8 + q] = a0[q]; z[r][c8 + 4 + q] = a1[q]; }
    __syncthreads();
    int h8 = (tid & 7) * 8;
#pragma unroll
    for (int hh = 0; hh < 8; ++hh) {
        int h = h8 + hh;
        float s = Wb[h];
        for (int c = 0; c < 64; ++c) s += z[r][c] * w[h][c];
        hidden[(size_t)(i0 + r) * 64 + h] = s;
        hl[r][h] = s;
    }
    __syncthreads();
    if (tid < 64) {
        float s = 0.f, q2 = 0.f;
#pragma unroll
        for (int rr = 0; rr < 32; ++rr) {
            float v = hl[rr][tid];
            s += v; q2 += v * v;
        }
        bsum[blockIdx.x * 64 + tid] = s;
        bsq[blockIdx.x * 64 + tid] = q2;
    }
}

__global__ __launch_bounds__(64) void bn_stats(const float* __restrict__ bsum,
        const float* __restrict__ bsq, const float* __restrict__ gamma,
        const float* __restrict__ beta, float* __restrict__ bnc) {
    int h = threadIdx.x;
    float s = 0.f, q = 0.f;
    for (int b = 0; b < 256; ++b) { s += bsum[b * 64 + h]; q += bsq[b * 64 + h]; }
    float mean = s / 8192.0f;
    float var = q / 8192.0f - mean * mean;
    float inv = rsqrtf(var + 1e-5f);
    float sc = gamma[h] * inv;
    bnc[h] = sc;
    bnc[64 + h] = beta[h] - mean * sc;
}

__global__ __launch_bounds__(256) void head(const float* __restrict__ hidden,
        const float* __restrict__ bnc, const float* __restrict__ Mw,
        const float* __restrict__ Mb, float* __restrict__ out0) {
    __shared__ float a[32][65];
    __shared__ float w[32][65];
    __shared__ float o[32][33];
    __shared__ float rowm[32];
    int i0 = blockIdx.x * 32;
    int tid = threadIdx.x;
    for (int e = tid * 4; e < 2048; e += 1024) {
        f32x4 v = *(const f32x4*)(Mw + e);
        int oo = e >> 6, c = e & 63;
#pragma unroll
        for (int q = 0; q < 4; ++q) w[oo][c + q] = v[q];
    }
    int r = tid >> 3, h8 = (tid & 7) * 8;
    const float* hp = hidden + (size_t)(i0 + r) * 64 + h8;
#pragma unroll
    for (int q = 0; q < 8; ++q) {
        int h = h8 + q;
        float v = hp[q] * bnc[h] + bnc[64 + h];
        a[r][h] = fmaxf(v, 0.f);
    }
    __syncthreads();
    int o4 = (tid & 7) * 4;
#pragma unroll
    for (int q = 0; q < 4; ++q) {
        int oo = o4 + q;
        float s = Mb[oo];
        for (int c = 0; c < 64; ++c) s += a[r][c] * w[oo][c];
        o[r][oo] = s;
    }
    __syncthreads();
    if (tid < 32) {
        float m = -3.0e38f;
#pragma unroll
        for (int c = 0; c < 32; ++c) m = fmaxf(m, o[tid][c]);
        float se = 0.f;
#pragma unroll
        for (int c = 0; c < 32; ++c) se += expf(o[tid][c] - m);
        rowm[tid] = m + logf(se);
    }
    __syncthreads();
    f32x4 v;
#pragma unroll
    for (int q = 0; q < 4; ++q) v[q] = o[r][o4 + q] - rowm[r];
    *(f32x4*)(out0 + (size_t)(i0 + r) * 32 + o4) = v;
}

extern "C" void kernel_launch(void* const* d_in, const int* in_sizes, int n_in,
                              void* d_out, int out_size, void* d_ws, size_t ws_size,
                              hipStream_t stream) {
    const float* X   = (const float*)d_in[0];
    const float* La  = (const float*)d_in[1];
    const float* U   = (const float*)d_in[2];
    const float* ve  = (const float*)d_in[3];
    const float* ve2 = (const float*)d_in[4];
    const float* Ww  = (const float*)d_in[5];
    const float* Wb  = (const float*)d_in[6];
    const float* gam = (const float*)d_in[7];
    const float* bet = (const float*)d_in[8];
    const float* Mw  = (const float*)d_in[9];
    const float* Mb  = (const float*)d_in[10];
    float* out0 = (float*)d_out;
    float* hidden = (float*)d_out + (size_t)NN * 32;   // output 1 region

    char* ws = (char*)d_ws;
    float* V1   = (float*)ws;                             // 32 KB
    float* V2   = (float*)(ws + 32768);                   // 32 KB
    float* bsum = (float*)(ws + 65536);                   // 64 KB
    float* bsq  = (float*)(ws + 131072);                  // 64 KB
    float* bnc  = (float*)(ws + 196608);                  // 512 B
    unsigned short* FB = (unsigned short*)(ws + 262144);  // 1 MB frag-major bf16
    float* P    = (float*)(ws + (2u << 20));              // 16 MB [SK][NN][64]
    float* Pt   = (float*)(ws + (20u << 20));             // 16 MB [SK][64][NN]
    unsigned short* Ubf = (unsigned short*)(ws + (64u << 20));  // 128 MB bf16 U

    prep_v<<<32, 256, 0, stream>>>(La, ve, ve2, V1, V2);
    // FB = frag(X)
    reduce_t<<<256, 256, 0, stream>>>(X, 1, FB);
    // T1^T partials = X^T @ U   (t-mode f32; emits Ubf row-major)
    spec_f32<1><<<dim3(NN / 64, SK), 256, 0, stream>>>(U, FB, Pt, Ubf);
    // FB = frag(V1 .* T1)
    reduce2<<<256, 256, 0, stream>>>(Pt, V1, FB);
    // Z1 = U @ S1   (n-mode bf16, prefetched FB)
    spec_nbf<<<dim3(NN / 64, SK), 256, 0, stream>>>(Ubf, FB, P);
    // FB = frag(Z1)
    reduce_t<<<256, 256, 0, stream>>>(P, SK, FB);
    // T2^T partials = Z1^T @ U  (t-mode f32)
    spec_f32<0><<<dim3(NN / 64, SK), 256, 0, stream>>>(U, FB, Pt, nullptr);
    // FB = frag(V2 .* T2)
    reduce2<<<256, 256, 0, stream>>>(Pt, V2, FB);
    // Z2 = U @ S2   (n-mode bf16, prefetched FB)
    spec_nbf<<<dim3(NN / 64, SK), 256, 0, stream>>>(Ubf, FB, P);
    // hidden = Z2 @ Ww^T + Wb  (+ BN partial stats)
    reduce_linear<<<256, 256, 0, stream>>>(P, Ww, Wb, hidden, bsum, bsq);
    bn_stats<<<1, 64, 0, stream>>>(bsum, bsq, gam, bet, bnc);
    head<<<256, 256, 0, stream>>>(hidden, bnc, Mw, Mb, out0);
}

// Round 16
// 293.088 us; speedup vs baseline: 1.1053x; 1.1053x over previous
//
#include <hip/hip_runtime.h>
#include <hip/hip_bf16.h>

typedef __attribute__((ext_vector_type(4))) float f32x4;
typedef __attribute__((ext_vector_type(8))) short bf16x8;
typedef __attribute__((ext_vector_type(8))) unsigned short u16x8;

#define NN 8192
#define SK 16
#define KSL (NN / SK)      // 512 k per WG
#define NT (KSL / 64)      // 8 tiles of 64 k

__device__ __forceinline__ unsigned short f2bf(float f) {
    unsigned int u = __float_as_uint(f);
    u += 0x7fffu + ((u >> 16) & 1u);
    return (unsigned short)(u >> 16);
}

__device__ __forceinline__ void gload16(const void* g, void* l) {
    __builtin_amdgcn_global_load_lds(
        (const __attribute__((address_space(1))) unsigned int*)g,
        (__attribute__((address_space(3))) unsigned int*)l, 16, 0, 0);
}

__global__ __launch_bounds__(256) void prep_v(const float* __restrict__ La,
        const float* __restrict__ ve, const float* __restrict__ ve2,
        float* __restrict__ V1, float* __restrict__ V2) {
    int i = blockIdx.x * 256 + threadIdx.x;
    float la = La[i];
    V1[i] = powf(la, ve[0]);
    float b = 2.0f * (la - 1e-8f) - 1.0f;
    V2[i] = powf(b * b + 1.0f, ve2[0]);
}

// ---------------------------------------------------------------------------
// FB frag layout (small matrix M[8192][64]):
//   FB[((b*4+nf)*64 + l)*8 + s] = M[32b + 8(l>>4) + s][16nf + (l&15)]
//
// spec_pass<0> (n): C[i][j]  = sum_k U[i][k]*S[k][j]; out P[sk][NN][64]
// spec_pass<1> (t): C'[m][n] = sum_k M[k][m]*U[k][n]; out Pt[sk][64][NN]
// U f32, 64x64 16KB tiles via global_load_lds (dbuf, source-XOR-swizzle,
// LDS linear). 32KB LDS/block + low VGPR (single inline FB, issued BEFORE
// the next-tile STAGE so its vmcnt wait leaves staging in flight) ->
// __launch_bounds__(256,5): 5 resident blocks/CU (160KB LDS), grid 2048.
// ---------------------------------------------------------------------------
template<int TM>
__global__ __launch_bounds__(256, 5) void spec_pass(const float* __restrict__ U,
        const unsigned short* __restrict__ FB, float* __restrict__ Pout) {
    __shared__ float tile[2][4096];          // 2 x 16 KB
    const int tid = threadIdx.x;
    const int w = tid >> 6, l = tid & 63;
    const int lm = l & 15, g = l >> 4;
    const int x0 = blockIdx.x * 64;          // n: row-block; t: col-block
    const int kbase = blockIdx.y * KSL;
    const int kb0 = kbase >> 5;
    const unsigned short* fbL = FB + (size_t)l * 8;

    f32x4 acc[4];
#pragma unroll
    for (int f = 0; f < 4; ++f) acc[f] = (f32x4)0.f;

#define STAGE(B, CT)                                                           \
    do {                                                                       \
        _Pragma("unroll")                                                      \
        for (int q_ = 0; q_ < 4; ++q_) {                                       \
            const int cc_ = 4 * w + q_;                                        \
            const int row_ = 4 * cc_ + (l >> 4);                               \
            const int su_ = (l & 15) ^ (row_ & 7);                             \
            const float* gp_ = U +                                             \
                (size_t)(TM ? (kbase + (CT) * 64 + row_) : (x0 + row_)) * NN + \
                (TM ? x0 : (kbase + (CT) * 64)) + su_ * 4;                     \
            gload16(gp_, &tile[B][cc_ * 256]);                                 \
        }                                                                      \
    } while (0)

#define LOADFB(R, CT)                                                          \
    do {                                                                       \
        _Pragma("unroll")                                                      \
        for (int sp_ = 0; sp_ < 2; ++sp_)                                      \
            _Pragma("unroll")                                                  \
            for (int f_ = 0; f_ < 4; ++f_)                                     \
                R[sp_][f_] = *(const bf16x8*)(fbL +                            \
                    ((size_t)((kb0 + 2 * (CT) + sp_) * 4 + f_)) * 512);        \
    } while (0)

#define COMPUTE(B, FBR)                                                        \
    do {                                                                       \
        _Pragma("unroll")                                                      \
        for (int sp_ = 0; sp_ < 2; ++sp_) {                                    \
            if (!TM) {                                                         \
                const float* rp_ = &tile[B][(16 * w + lm) * 64];               \
                const int m7_ = lm & 7;                                        \
                f32x4 p0_ = *(const f32x4*)(rp_ +                              \
                    (((8 * sp_ + 2 * g) ^ m7_) << 2));                         \
                f32x4 p1_ = *(const f32x4*)(rp_ +                              \
                    (((8 * sp_ + 2 * g + 1) ^ m7_) << 2));                     \
                bf16x8 afr_;                                                   \
                _Pragma("unroll")                                              \
                for (int j_ = 0; j_ < 4; ++j_) {                               \
                    afr_[j_]     = (short)f2bf(p0_[j_]);                       \
                    afr_[4 + j_] = (short)f2bf(p1_[j_]);                       \
                }                                                              \
                _Pragma("unroll")                                              \
                for (int f_ = 0; f_ < 4; ++f_)                                 \
                    acc[f_] = __builtin_amdgcn_mfma_f32_16x16x32_bf16(         \
                        afr_, FBR[sp_][f_], acc[f_], 0, 0, 0);                 \
            } else {                                                           \
                bf16x8 bfr_;                                                   \
                _Pragma("unroll")                                              \
                for (int s_ = 0; s_ < 8; ++s_)                                 \
                    bfr_[s_] = (short)f2bf(tile[B][                            \
                        (32 * sp_ + 8 * g + s_) * 64 +                         \
                        (((4 * w + (lm >> 2)) ^ s_) << 2) + (lm & 3)]);        \
                _Pragma("unroll")                                              \
                for (int f_ = 0; f_ < 4; ++f_)                                 \
                    acc[f_] = __builtin_amdgcn_mfma_f32_16x16x32_bf16(         \
                        FBR[sp_][f_], bfr_, acc[f_], 0, 0, 0);                 \
            }                                                                  \
        }                                                                      \
    } while (0)

    STAGE(0, 0);
    __syncthreads();
#pragma unroll 1
    for (int c = 0; c < NT; c += 2) {
        {
            bf16x8 fb[2][4];
            LOADFB(fb, c);             // issued first: compute's wait on fb
            STAGE(1, c + 1);           // leaves this staging in flight
            COMPUTE(0, fb);
        }
        __syncthreads();
        {
            bf16x8 fb[2][4];
            LOADFB(fb, c + 1);
            if (c + 2 < NT) STAGE(0, c + 2);
            COMPUTE(1, fb);
        }
        __syncthreads();
    }
#undef STAGE
#undef LOADFB
#undef COMPUTE

    if (!TM) {
        float* Pp = Pout + (size_t)blockIdx.y * NN * 64;
#pragma unroll
        for (int f = 0; f < 4; ++f)
#pragma unroll
            for (int r = 0; r < 4; ++r)
                Pp[(size_t)(x0 + 16 * w + 4 * g + r) * 64 + f * 16 + lm] = acc[f][r];
    } else {
        float* Pp = Pout + (size_t)blockIdx.y * 64 * NN;
#pragma unroll
        for (int f = 0; f < 4; ++f)
#pragma unroll
            for (int r = 0; r < 4; ++r)
                Pp[(size_t)(16 * f + 4 * g + r) * NN + x0 + 16 * w + lm] = acc[f][r];
    }
}

// reduce2: FB = frag( colscale(V) * sum_sk Pt[sk][ch][i] ), Pt [SK][64][NN]
__global__ __launch_bounds__(256) void reduce2(const float* __restrict__ Pt,
        const float* __restrict__ V, unsigned short* __restrict__ FB) {
    int b = blockIdx.x;
    int t = threadIdx.x;
    int nf = t >> 6, l = t & 63, lm = l & 15, g = l >> 4;
    int ch = 16 * nf + lm;
    int ib = 32 * b + 8 * g;
    f32x4 s0 = (f32x4)0.f, s1 = (f32x4)0.f;
#pragma unroll
    for (int sk = 0; sk < SK; ++sk) {
        const float* p = Pt + (size_t)(sk * 64 + ch) * NN + ib;
        s0 += *(const f32x4*)p;
        s1 += *(const f32x4*)(p + 4);
    }
    f32x4 v0 = *(const f32x4*)(V + ib);
    f32x4 v1 = *(const f32x4*)(V + ib + 4);
    u16x8 o;
#pragma unroll
    for (int c = 0; c < 4; ++c) {
        o[c]     = f2bf(s0[c] * v0[c]);
        o[4 + c] = f2bf(s1[c] * v1[c]);
    }
    *(u16x8*)(FB + ((size_t)(b * 4 + nf) * 64 + l) * 8) = o;
}

// reduce_t: FB = frag( sum_sk M[sk][i][j] ), M [nsk][NN][64] row-major.
__global__ __launch_bounds__(256) void reduce_t(const float* __restrict__ M, int nsk,
        unsigned short* __restrict__ FB) {
    __shared__ float T[32][65];
    int b = blockIdx.x;
    int i0 = b * 32;
    int tid = threadIdx.x;
    int il = tid >> 3, jq = (tid & 7) * 8;
    f32x4 s0 = (f32x4)0.f, s1 = (f32x4)0.f;
    for (int k = 0; k < nsk; ++k) {
        const float* p = M + ((size_t)k * NN + i0 + il) * 64 + jq;
        s0 += *(const f32x4*)p;
        s1 += *(const f32x4*)(p + 4);
    }
#pragma unroll
    for (int c = 0; c < 4; ++c) {
        T[il][jq + c] = s0[c];
        T[il][jq + 4 + c] = s1[c];
    }
    __syncthreads();
    int nf = tid >> 6, l = tid & 63, g = l >> 4, lm = l & 15;
    u16x8 o;
#pragma unroll
    for (int s = 0; s < 8; ++s) o[s] = f2bf(T[8 * g + s][16 * nf + lm]);
    *(u16x8*)(FB + ((size_t)(b * 4 + nf) * 64 + l) * 8) = o;
}

// Z2 = sum of partials; hidden = Z2 @ Ww^T + Wb; also per-block BN partial sums.
__global__ __launch_bounds__(256) void reduce_linear(const float* __restrict__ P,
        const float* __restrict__ Ww, const float* __restrict__ Wb,
        float* __restrict__ hidden, float* __restrict__ bsum, float* __restrict__ bsq) {
    __shared__ float z[32][65];
    __shared__ float w[64][65];
    __shared__ float hl[32][65];
    int i0 = blockIdx.x * 32;
    int tid = threadIdx.x;
    for (int e = tid * 4; e < 4096; e += 1024) {
        f32x4 v = *(const f32x4*)(Ww + e);
        int h = e >> 6, c = e & 63;
#pragma unroll
        for (int q = 0; q < 4; ++q) w[h][c + q] = v[q];
    }
    int r = tid >> 3, c8 = (tid & 7) * 8;
    f32x4 a0 = (f32x4)0.f, a1 = (f32x4)0.f;
    for (int k = 0; k < SK; ++k) {
        const float* p = P + ((size_t)k * NN + i0 + r) * 64 + c8;
        a0 += *(const f32x4*)p;
        a1 += *(const f32x4*)(p + 4);
    }
#pragma unroll
    for (int q = 0; q < 4; ++q) { z[r][c8 + q] = a0[q]; z[r][c8 + 4 + q] = a1[q]; }
    __syncthreads();
    int h8 = (tid & 7) * 8;
#pragma unroll
    for (int hh = 0; hh < 8; ++hh) {
        int h = h8 + hh;
        float s = Wb[h];
        for (int c = 0; c < 64; ++c) s += z[r][c] * w[h][c];
        hidden[(size_t)(i0 + r) * 64 + h] = s;
        hl[r][h] = s;
    }
    __syncthreads();
    if (tid < 64) {
        float s = 0.f, q2 = 0.f;
#pragma unroll
        for (int rr = 0; rr < 32; ++rr) {
            float v = hl[rr][tid];
            s += v; q2 += v * v;
        }
        bsum[blockIdx.x * 64 + tid] = s;
        bsq[blockIdx.x * 64 + tid] = q2;
    }
}

__global__ __launch_bounds__(64) void bn_stats(const float* __restrict__ bsum,
        const float* __restrict__ bsq, const float* __restrict__ gamma,
        const float* __restrict__ beta, float* __restrict__ bnc) {
    int h = threadIdx.x;
    float s = 0.f, q = 0.f;
    for (int b = 0; b < 256; ++b) { s += bsum[b * 64 + h]; q += bsq[b * 64 + h]; }
    float mean = s / 8192.0f;
    float var = q / 8192.0f - mean * mean;
    float inv = rsqrtf(var + 1e-5f);
    float sc = gamma[h] * inv;
    bnc[h] = sc;
    bnc[64 + h] = beta[h] - mean * sc;
}

__global__ __launch_bounds__(256) void head(const float* __restrict__ hidden,
        const float* __restrict__ bnc, const float* __restrict__ Mw,
        const float* __restrict__ Mb, float* __restrict__ out0) {
    __shared__ float a[32][65];
    __shared__ float w[32][65];
    __shared__ float o[32][33];
    __shared__ float rowm[32];
    int i0 = blockIdx.x * 32;
    int tid = threadIdx.x;
    for (int e = tid * 4; e < 2048; e += 1024) {
        f32x4 v = *(const f32x4*)(Mw + e);
        int oo = e >> 6, c = e & 63;
#pragma unroll
        for (int q = 0; q < 4; ++q) w[oo][c + q] = v[q];
    }
    int r = tid >> 3, h8 = (tid & 7) * 8;
    const float* hp = hidden + (size_t)(i0 + r) * 64 + h8;
#pragma unroll
    for (int q = 0; q < 8; ++q) {
        int h = h8 + q;
        float v = hp[q] * bnc[h] + bnc[64 + h];
        a[r][h] = fmaxf(v, 0.f);
    }
    __syncthreads();
    int o4 = (tid & 7) * 4;
#pragma unroll
    for (int q = 0; q < 4; ++q) {
        int oo = o4 + q;
        float s = Mb[oo];
        for (int c = 0; c < 64; ++c) s += a[r][c] * w[oo][c];
        o[r][oo] = s;
    }
    __syncthreads();
    if (tid < 32) {
        float m = -3.0e38f;
#pragma unroll
        for (int c = 0; c < 32; ++c) m = fmaxf(m, o[tid][c]);
        float se = 0.f;
#pragma unroll
        for (int c = 0; c < 32; ++c) se += expf(o[tid][c] - m);
        rowm[tid] = m + logf(se);
    }
    __syncthreads();
    f32x4 v;
#pragma unroll
    for (int q = 0; q < 4; ++q) v[q] = o[r][o4 + q] - rowm[r];
    *(f32x4*)(out0 + (size_t)(i0 + r) * 32 + o4) = v;
}

extern "C" void kernel_launch(void* const* d_in, const int* in_sizes, int n_in,
                              void* d_out, int out_size, void* d_ws, size_t ws_size,
                              hipStream_t stream) {
    const float* X   = (const float*)d_in[0];
    const float* La  = (const float*)d_in[1];
    const float* U   = (const float*)d_in[2];
    const float* ve  = (const float*)d_in[3];
    const float* ve2 = (const float*)d_in[4];
    const float* Ww  = (const float*)d_in[5];
    const float* Wb  = (const float*)d_in[6];
    const float* gam = (const float*)d_in[7];
    const float* bet = (const float*)d_in[8];
    const float* Mw  = (const float*)d_in[9];
    const float* Mb  = (const float*)d_in[10];
    float* out0 = (float*)d_out;
    float* hidden = (float*)d_out + (size_t)NN * 32;   // output 1 region

    char* ws = (char*)d_ws;
    float* V1   = (float*)ws;                             // 32 KB
    float* V2   = (float*)(ws + 32768);                   // 32 KB
    float* bsum = (float*)(ws + 65536);                   // 64 KB
    float* bsq  = (float*)(ws + 131072);                  // 64 KB
    float* bnc  = (float*)(ws + 196608);                  // 512 B
    unsigned short* FB = (unsigned short*)(ws + 262144);  // 1 MB frag-major bf16
    float* P    = (float*)(ws + (2u << 20));              // 32 MB [SK][NN][64]
    float* Pt   = (float*)(ws + (36u << 20));             // 32 MB [SK][64][NN]

    prep_v<<<32, 256, 0, stream>>>(La, ve, ve2, V1, V2);
    // FB = frag(X)
    reduce_t<<<256, 256, 0, stream>>>(X, 1, FB);
    // T1^T partials = X^T @ U
    spec_pass<1><<<dim3(NN / 64, SK), 256, 0, stream>>>(U, FB, Pt);
    // FB = frag(V1 .* T1)
    reduce2<<<256, 256, 0, stream>>>(Pt, V1, FB);
    // Z1 = U @ S1
    spec_pass<0><<<dim3(NN / 64, SK), 256, 0, stream>>>(U, FB, P);
    // FB = frag(Z1)
    reduce_t<<<256, 256, 0, stream>>>(P, SK, FB);
    // T2^T partials = Z1^T @ U
    spec_pass<1><<<dim3(NN / 64, SK), 256, 0, stream>>>(U, FB, Pt);
    // FB = frag(V2 .* T2)
    reduce2<<<256, 256, 0, stream>>>(Pt, V2, FB);
    // Z2 = U @ S2
    spec_pass<0><<<dim3(NN / 64, SK), 256, 0, stream>>>(U, FB, P);
    // hidden = Z2 @ Ww^T + Wb  (+ BN partial stats)
    reduce_linear<<<256, 256, 0, stream>>>(P, Ww, Wb, hidden, bsum, bsq);
    bn_stats<<<1, 64, 0, stream>>>(bsum, bsq, gam, bet, bnc);
    head<<<256, 256, 0, stream>>>(hidden, bnc, Mw, Mb, out0);
}

// Round 17
// 234.451 us; speedup vs baseline: 1.3818x; 1.2501x over previous
//
#include <hip/hip_runtime.h>
#include <hip/hip_bf16.h>

typedef __attribute__((ext_vector_type(4))) float f32x4;
typedef __attribute__((ext_vector_type(8))) short bf16x8;
typedef __attribute__((ext_vector_type(8))) unsigned short u16x8;

#define NN 8192
#define SK 8
#define KSL (NN / SK)      // 1024 k per WG
#define NT (KSL / 64)      // 16 tiles of 64 k

__device__ __forceinline__ unsigned short f2bf(float f) {
    unsigned int u = __float_as_uint(f);
    u += 0x7fffu + ((u >> 16) & 1u);
    return (unsigned short)(u >> 16);
}

__device__ __forceinline__ float bf2f(unsigned short h) {
    return __uint_as_float((unsigned int)h << 16);
}

__device__ __forceinline__ void gload16(const void* g, void* l) {
    __builtin_amdgcn_global_load_lds(
        (const __attribute__((address_space(1))) unsigned int*)g,
        (__attribute__((address_space(3))) unsigned int*)l, 16, 0, 0);
}

#define VMW(N) asm volatile("s_waitcnt vmcnt(" #N ")" ::: "memory")
#define SBAR() do { __builtin_amdgcn_sched_barrier(0);                         \
                    __builtin_amdgcn_s_barrier();                              \
                    __builtin_amdgcn_sched_barrier(0); } while (0)

__global__ __launch_bounds__(256) void prep_v(const float* __restrict__ La,
        const float* __restrict__ ve, const float* __restrict__ ve2,
        float* __restrict__ V1, float* __restrict__ V2) {
    int i = blockIdx.x * 256 + threadIdx.x;
    float la = La[i];
    V1[i] = powf(la, ve[0]);
    float b = 2.0f * (la - 1e-8f) - 1.0f;
    V2[i] = powf(b * b + 1.0f, ve2[0]);
}

// ---------------------------------------------------------------------------
// FB frag layout (small matrix M[8192][64]):
//   FB[((b*4+nf)*64 + l)*8 + s] = M[32b + 8(l>>4) + s][16nf + (l&15)]
//
// spec_pass<0> (n): C[i][j]  = sum_k U[i][k]*S[k][j]; out P[sk][NN][64] bf16
// spec_pass<1> (t): C'[m][n] = sum_k M[k][m]*U[k][n]; out Pt[sk][64][NN] bf16
// U f32, 64x64 16KB tiles via global_load_lds (dbuf, source-XOR-swizzle,
// LDS linear). Counted-vmcnt pipeline (r13 record structure, unchanged):
// STAGE(t+1)+LOADFB(t+1) issued first; vmcnt(20) retires only tile-t's
// stage loads; raw s_barrier keeps t+1's 12 VMEM ops in flight.
// ---------------------------------------------------------------------------
template<int TM>
__global__ __launch_bounds__(256, 4) void spec_pass(const float* __restrict__ U,
        const unsigned short* __restrict__ FB, unsigned short* __restrict__ Pout) {
    __shared__ float tile[2][4096];          // 2 x 16 KB
    const int tid = threadIdx.x;
    const int w = tid >> 6, l = tid & 63;
    const int lm = l & 15, g = l >> 4;
    const int x0 = blockIdx.x * 64;          // n: row-block; t: col-block
    const int kbase = blockIdx.y * KSL;
    const int kb0 = kbase >> 5;
    const unsigned short* fbL = FB + (size_t)l * 8;

    f32x4 acc[4];
#pragma unroll
    for (int f = 0; f < 4; ++f) acc[f] = (f32x4)0.f;

#define STAGE(B, CT)                                                           \
    do {                                                                       \
        _Pragma("unroll")                                                      \
        for (int q_ = 0; q_ < 4; ++q_) {                                       \
            const int cc_ = 4 * w + q_;                                        \
            const int row_ = 4 * cc_ + (l >> 4);                               \
            const int su_ = (l & 15) ^ (row_ & 7);                             \
            const float* gp_ = U +                                             \
                (size_t)(TM ? (kbase + (CT) * 64 + row_) : (x0 + row_)) * NN + \
                (TM ? x0 : (kbase + (CT) * 64)) + su_ * 4;                     \
            gload16(gp_, &tile[B][cc_ * 256]);                                 \
        }                                                                      \
    } while (0)

#define LOADFB(R, CT)                                                          \
    do {                                                                       \
        _Pragma("unroll")                                                      \
        for (int sp_ = 0; sp_ < 2; ++sp_)                                      \
            _Pragma("unroll")                                                  \
            for (int f_ = 0; f_ < 4; ++f_)                                     \
                R[sp_][f_] = *(const bf16x8*)(fbL +                            \
                    ((size_t)((kb0 + 2 * (CT) + sp_) * 4 + f_)) * 512);        \
    } while (0)

#define COMPUTE(B, FBR)                                                        \
    do {                                                                       \
        _Pragma("unroll")                                                      \
        for (int sp_ = 0; sp_ < 2; ++sp_) {                                    \
            if (!TM) {                                                         \
                const float* rp_ = &tile[B][(16 * w + lm) * 64];               \
                const int m7_ = lm & 7;                                        \
                f32x4 p0_ = *(const f32x4*)(rp_ +                              \
                    (((8 * sp_ + 2 * g) ^ m7_) << 2));                         \
                f32x4 p1_ = *(const f32x4*)(rp_ +                              \
                    (((8 * sp_ + 2 * g + 1) ^ m7_) << 2));                     \
                bf16x8 afr_;                                                   \
                _Pragma("unroll")                                              \
                for (int j_ = 0; j_ < 4; ++j_) {                               \
                    afr_[j_]     = (short)f2bf(p0_[j_]);                       \
                    afr_[4 + j_] = (short)f2bf(p1_[j_]);                       \
                }                                                              \
                _Pragma("unroll")                                              \
                for (int f_ = 0; f_ < 4; ++f_)                                 \
                    acc[f_] = __builtin_amdgcn_mfma_f32_16x16x32_bf16(         \
                        afr_, FBR[sp_][f_], acc[f_], 0, 0, 0);                 \
            } else {                                                           \
                bf16x8 bfr_;                                                   \
                _Pragma("unroll")                                              \
                for (int s_ = 0; s_ < 8; ++s_)                                 \
                    bfr_[s_] = (short)f2bf(tile[B][                            \
                        (32 * sp_ + 8 * g + s_) * 64 +                         \
                        (((4 * w + (lm >> 2)) ^ s_) << 2) + (lm & 3)]);        \
                _Pragma("unroll")                                              \
                for (int f_ = 0; f_ < 4; ++f_)                                 \
                    acc[f_] = __builtin_amdgcn_mfma_f32_16x16x32_bf16(         \
                        FBR[sp_][f_], bfr_, acc[f_], 0, 0, 0);                 \
            }                                                                  \
        }                                                                      \
    } while (0)

    bf16x8 fbA[2][4], fbB[2][4];
    // prologue: stage-0 then fb-0  -> outstanding [s0:4][f0:8]
    STAGE(0, 0);
    LOADFB(fbA, 0);
#pragma unroll 1
    for (int c = 0; c < NT; c += 2) {
        // tile c (buf 0, fbA)
        STAGE(1, c + 1);
        LOADFB(fbB, c + 1);
        // outstanding: [s_c:4][f_c:8][s_{c+1}:4][f_{c+1}:8] = 24
        VMW(20);                       // retire s_c only
        SBAR();
        COMPUTE(0, fbA);               // compiler auto-waits f_c (vmcnt 12)
        SBAR();
        // tile c+1 (buf 1, fbB)
        if (c + 2 < NT) {
            STAGE(0, c + 2);
            LOADFB(fbA, c + 2);
            VMW(20);                   // retire s_{c+1}
        } else {
            VMW(8);                    // [s_{c+1}:4][f_{c+1}:8] -> retire s
        }
        SBAR();
        COMPUTE(1, fbB);
        SBAR();
    }
#undef STAGE
#undef LOADFB
#undef COMPUTE

    if (!TM) {
        unsigned short* Pp = Pout + (size_t)blockIdx.y * NN * 64;
#pragma unroll
        for (int f = 0; f < 4; ++f)
#pragma unroll
            for (int r = 0; r < 4; ++r)
                Pp[(size_t)(x0 + 16 * w + 4 * g + r) * 64 + f * 16 + lm] =
                    f2bf(acc[f][r]);
    } else {
        unsigned short* Pp = Pout + (size_t)blockIdx.y * 64 * NN;
#pragma unroll
        for (int f = 0; f < 4; ++f)
#pragma unroll
            for (int r = 0; r < 4; ++r)
                Pp[(size_t)(16 * f + 4 * g + r) * NN + x0 + 16 * w + lm] =
                    f2bf(acc[f][r]);
    }
}

// reduce2: FB = frag( colscale(V) * sum_sk Pt[sk][ch][i] ), Pt bf16 [SK][64][NN]
__global__ __launch_bounds__(256) void reduce2(const unsigned short* __restrict__ Pt,
        const float* __restrict__ V, unsigned short* __restrict__ FB) {
    int b = blockIdx.x;
    int t = threadIdx.x;
    int nf = t >> 6, l = t & 63, lm = l & 15, g = l >> 4;
    int ch = 16 * nf + lm;
    int ib = 32 * b + 8 * g;
    float s[8];
#pragma unroll
    for (int c = 0; c < 8; ++c) s[c] = 0.f;
#pragma unroll
    for (int sk = 0; sk < SK; ++sk) {
        u16x8 v = *(const u16x8*)(Pt + (size_t)(sk * 64 + ch) * NN + ib);
#pragma unroll
        for (int c = 0; c < 8; ++c) s[c] += bf2f(v[c]);
    }
    f32x4 v0 = *(const f32x4*)(V + ib);
    f32x4 v1 = *(const f32x4*)(V + ib + 4);
    u16x8 o;
#pragma unroll
    for (int c = 0; c < 4; ++c) {
        o[c]     = f2bf(s[c] * v0[c]);
        o[4 + c] = f2bf(s[4 + c] * v1[c]);
    }
    *(u16x8*)(FB + ((size_t)(b * 4 + nf) * 64 + l) * 8) = o;
}

// reduce_t<BF>: FB = frag( sum_sk M[sk][i][j] ).
//   BF=0: M f32 (the X input, nsk=1). BF=1: M bf16 partials [nsk][NN][64].
template<int BF>
__global__ __launch_bounds__(256) void reduce_t(const void* __restrict__ M, int nsk,
        unsigned short* __restrict__ FB) {
    __shared__ float T[32][65];
    int b = blockIdx.x;
    int i0 = b * 32;
    int tid = threadIdx.x;
    int il = tid >> 3, jq = (tid & 7) * 8;
    float s[8];
#pragma unroll
    for (int c = 0; c < 8; ++c) s[c] = 0.f;
    for (int k = 0; k < nsk; ++k) {
        if (!BF) {
            const float* p = (const float*)M + ((size_t)k * NN + i0 + il) * 64 + jq;
            f32x4 a = *(const f32x4*)p;
            f32x4 bq = *(const f32x4*)(p + 4);
#pragma unroll
            for (int c = 0; c < 4; ++c) { s[c] += a[c]; s[4 + c] += bq[c]; }
        } else {
            u16x8 v = *(const u16x8*)((const unsigned short*)M +
                ((size_t)k * NN + i0 + il) * 64 + jq);
#pragma unroll
            for (int c = 0; c < 8; ++c) s[c] += bf2f(v[c]);
        }
    }
#pragma unroll
    for (int c = 0; c < 8; ++c) T[il][jq + c] = s[c];
    __syncthreads();
    int nf = tid >> 6, l = tid & 63, g = l >> 4, lm = l & 15;
    u16x8 o;
#pragma unroll
    for (int q = 0; q < 8; ++q) o[q] = f2bf(T[8 * g + q][16 * nf + lm]);
    *(u16x8*)(FB + ((size_t)(b * 4 + nf) * 64 + l) * 8) = o;
}

// Z2 = sum of bf16 partials; hidden = Z2 @ Ww^T + Wb; + per-block BN sums.
__global__ __launch_bounds__(256) void reduce_linear(
        const unsigned short* __restrict__ P,
        const float* __restrict__ Ww, const float* __restrict__ Wb,
        float* __restrict__ hidden, float* __restrict__ bsum, float* __restrict__ bsq) {
    __shared__ float z[32][65];
    __shared__ float w[64][65];
    __shared__ float hl[32][65];
    int i0 = blockIdx.x * 32;
    int tid = threadIdx.x;
    for (int e = tid * 4; e < 4096; e += 1024) {
        f32x4 v = *(const f32x4*)(Ww + e);
        int h = e >> 6, c = e & 63;
#pragma unroll
        for (int q = 0; q < 4; ++q) w[h][c + q] = v[q];
    }
    int r = tid >> 3, c8 = (tid & 7) * 8;
    float s[8];
#pragma unroll
    for (int q = 0; q < 8; ++q) s[q] = 0.f;
    for (int k = 0; k < SK; ++k) {
        u16x8 v = *(const u16x8*)(P + ((size_t)k * NN + i0 + r) * 64 + c8);
#pragma unroll
        for (int q = 0; q < 8; ++q) s[q] += bf2f(v[q]);
    }
#pragma unroll
    for (int q = 0; q < 8; ++q) z[r][c8 + q] = s[q];
    __syncthreads();
    int h8 = (tid & 7) * 8;
#pragma unroll
    for (int hh = 0; hh < 8; ++hh) {
        int h = h8 + hh;
        float sv = Wb[h];
        for (int c = 0; c < 64; ++c) sv += z[r][c] * w[h][c];
        hidden[(size_t)(i0 + r) * 64 + h] = sv;
        hl[r][h] = sv;
    }
    __syncthreads();
    if (tid < 64) {
        float sv = 0.f, q2 = 0.f;
#pragma unroll
        for (int rr = 0; rr < 32; ++rr) {
            float v = hl[rr][tid];
            sv += v; q2 += v * v;
        }
        bsum[blockIdx.x * 64 + tid] = sv;
        bsq[blockIdx.x * 64 + tid] = q2;
    }
}

__global__ __launch_bounds__(64) void bn_stats(const float* __restrict__ bsum,
        const float* __restrict__ bsq, const float* __restrict__ gamma,
        const float* __restrict__ beta, float* __restrict__ bnc) {
    int h = threadIdx.x;
    float s = 0.f, q = 0.f;
    for (int b = 0; b < 256; ++b) { s += bsum[b * 64 + h]; q += bsq[b * 64 + h]; }
    float mean = s / 8192.0f;
    float var = q / 8192.0f - mean * mean;
    float inv = rsqrtf(var + 1e-5f);
    float sc = gamma[h] * inv;
    bnc[h] = sc;
    bnc[64 + h] = beta[h] - mean * sc;
}

__global__ __launch_bounds__(256) void head(const float* __restrict__ hidden,
        const float* __restrict__ bnc, const float* __restrict__ Mw,
        const float* __restrict__ Mb, float* __restrict__ out0) {
    __shared__ float a[32][65];
    __shared__ float w[32][65];
    __shared__ float o[32][33];
    __shared__ float rowm[32];
    int i0 = blockIdx.x * 32;
    int tid = threadIdx.x;
    for (int e = tid * 4; e < 2048; e += 1024) {
        f32x4 v = *(const f32x4*)(Mw + e);
        int oo = e >> 6, c = e & 63;
#pragma unroll
        for (int q = 0; q < 4; ++q) w[oo][c + q] = v[q];
    }
    int r = tid >> 3, h8 = (tid & 7) * 8;
    const float* hp = hidden + (size_t)(i0 + r) * 64 + h8;
#pragma unroll
    for (int q = 0; q < 8; ++q) {
        int h = h8 + q;
        float v = hp[q] * bnc[h] + bnc[64 + h];
        a[r][h] = fmaxf(v, 0.f);
    }
    __syncthreads();
    int o4 = (tid & 7) * 4;
#pragma unroll
    for (int q = 0; q < 4; ++q) {
        int oo = o4 + q;
        float s = Mb[oo];
        for (int c = 0; c < 64; ++c) s += a[r][c] * w[oo][c];
        o[r][oo] = s;
    }
    __syncthreads();
    if (tid < 32) {
        float m = -3.0e38f;
#pragma unroll
        for (int c = 0; c < 32; ++c) m = fmaxf(m, o[tid][c]);
        float se = 0.f;
#pragma unroll
        for (int c = 0; c < 32; ++c) se += expf(o[tid][c] - m);
        rowm[tid] = m + logf(se);
    }
    __syncthreads();
    f32x4 v;
#pragma unroll
    for (int q = 0; q < 4; ++q) v[q] = o[r][o4 + q] - rowm[r];
    *(f32x4*)(out0 + (size_t)(i0 + r) * 32 + o4) = v;
}

extern "C" void kernel_launch(void* const* d_in, const int* in_sizes, int n_in,
                              void* d_out, int out_size, void* d_ws, size_t ws_size,
                              hipStream_t stream) {
    const float* X   = (const float*)d_in[0];
    const float* La  = (const float*)d_in[1];
    const float* U   = (const float*)d_in[2];
    const float* ve  = (const float*)d_in[3];
    const float* ve2 = (const float*)d_in[4];
    const float* Ww  = (const float*)d_in[5];
    const float* Wb  = (const float*)d_in[6];
    const float* gam = (const float*)d_in[7];
    const float* bet = (const float*)d_in[8];
    const float* Mw  = (const float*)d_in[9];
    const float* Mb  = (const float*)d_in[10];
    float* out0 = (float*)d_out;
    float* hidden = (float*)d_out + (size_t)NN * 32;   // output 1 region

    char* ws = (char*)d_ws;
    float* V1   = (float*)ws;                             // 32 KB
    float* V2   = (float*)(ws + 32768);                   // 32 KB
    float* bsum = (float*)(ws + 65536);                   // 64 KB
    float* bsq  = (float*)(ws + 131072);                  // 64 KB
    float* bnc  = (float*)(ws + 196608);                  // 512 B
    unsigned short* FB = (unsigned short*)(ws + 262144);  // 1 MB frag-major bf16
    unsigned short* P  = (unsigned short*)(ws + (2u << 20));   // 8 MB bf16
    unsigned short* Pt = (unsigned short*)(ws + (12u << 20));  // 8 MB bf16

    prep_v<<<32, 256, 0, stream>>>(La, ve, ve2, V1, V2);
    // FB = frag(X)
    reduce_t<0><<<256, 256, 0, stream>>>(X, 1, FB);
    // T1^T partials = X^T @ U
    spec_pass<1><<<dim3(NN / 64, SK), 256, 0, stream>>>(U, FB, Pt);
    // FB = frag(V1 .* T1)
    reduce2<<<256, 256, 0, stream>>>(Pt, V1, FB);
    // Z1 = U @ S1
    spec_pass<0><<<dim3(NN / 64, SK), 256, 0, stream>>>(U, FB, P);
    // FB = frag(Z1)
    reduce_t<1><<<256, 256, 0, stream>>>(P, SK, FB);
    // T2^T partials = Z1^T @ U
    spec_pass<1><<<dim3(NN / 64, SK), 256, 0, stream>>>(U, FB, Pt);
    // FB = frag(V2 .* T2)
    reduce2<<<256, 256, 0, stream>>>(Pt, V2, FB);
    // Z2 = U @ S2
    spec_pass<0><<<dim3(NN / 64, SK), 256, 0, stream>>>(U, FB, P);
    // hidden = Z2 @ Ww^T + Wb  (+ BN partial stats)
    reduce_linear<<<256, 256, 0, stream>>>(P, Ww, Wb, hidden, bsum, bsq);
    bn_stats<<<1, 64, 0, stream>>>(bsum, bsq, gam, bet, bnc);
    head<<<256, 256, 0, stream>>>(hidden, bnc, Mw, Mb, out0);
}

// Round 18
// 233.521 us; speedup vs baseline: 1.3873x; 1.0040x over previous
//
#include <hip/hip_runtime.h>
#include <hip/hip_bf16.h>

typedef __attribute__((ext_vector_type(4))) float f32x4;
typedef __attribute__((ext_vector_type(8))) short bf16x8;
typedef __attribute__((ext_vector_type(8))) unsigned short u16x8;

#define NN 8192
#define SK 8
#define KSL (NN / SK)      // 1024 k per WG
#define NT (KSL / 64)      // 16 tiles of 64 k

__device__ __forceinline__ unsigned short f2bf(float f) {
    unsigned int u = __float_as_uint(f);
    u += 0x7fffu + ((u >> 16) & 1u);
    return (unsigned short)(u >> 16);
}

__device__ __forceinline__ float bf2f(unsigned short h) {
    return __uint_as_float((unsigned int)h << 16);
}

__device__ __forceinline__ void gload16(const void* g, void* l) {
    __builtin_amdgcn_global_load_lds(
        (const __attribute__((address_space(1))) unsigned int*)g,
        (__attribute__((address_space(3))) unsigned int*)l, 16, 0, 0);
}

#define VMW(N) asm volatile("s_waitcnt vmcnt(" #N ")" ::: "memory")
#define SBAR() do { __builtin_amdgcn_sched_barrier(0);                         \
                    __builtin_amdgcn_s_barrier();                              \
                    __builtin_amdgcn_sched_barrier(0); } while (0)

__global__ __launch_bounds__(256) void prep_v(const float* __restrict__ La,
        const float* __restrict__ ve, const float* __restrict__ ve2,
        float* __restrict__ V1, float* __restrict__ V2) {
    int i = blockIdx.x * 256 + threadIdx.x;
    float la = La[i];
    V1[i] = powf(la, ve[0]);
    float b = 2.0f * (la - 1e-8f) - 1.0f;
    V2[i] = powf(b * b + 1.0f, ve2[0]);
}

// ---------------------------------------------------------------------------
// FB frag layout (small matrix M[8192][64]):
//   FB[((b*4+nf)*64 + l)*8 + s] = M[32b + 8(l>>4) + s][16nf + (l&15)]
//
// spec_pass<0> (n): C[i][j]  = sum_k U[i][k]*S[k][j]; out P[sk][NN][64] bf16
// spec_pass<1> (t): C'[m][n] = sum_k M[k][m]*U[k][n]; out Pt[sk][64][NN] bf16
// U f32, 64x64 16KB tiles via global_load_lds, 3-buffer rotation staged TWO
// tiles ahead (2-phase deadline slack). FIFO-exact vmcnt: per phase, issue
// LOADFB(t+1) then STAGE(t+2); queue ... fb_t, s_{t+1}, fb_{t+1}, s_{t+2};
// VMW(16) retires {fb_t, s_t} only. Tail: VMW(12) @ phase14, VMW(0) @ 15.
// ---------------------------------------------------------------------------
template<int TM>
__global__ __launch_bounds__(256, 4) void spec_pass(const float* __restrict__ U,
        const unsigned short* __restrict__ FB, unsigned short* __restrict__ Pout) {
    __shared__ float tile[3][4096];          // 3 x 16 KB
    const int tid = threadIdx.x;
    const int w = tid >> 6, l = tid & 63;
    const int lm = l & 15, g = l >> 4;
    const int x0 = blockIdx.x * 64;          // n: row-block; t: col-block
    const int kbase = blockIdx.y * KSL;
    const int kb0 = kbase >> 5;
    const unsigned short* fbL = FB + (size_t)l * 8;

    f32x4 acc[4];
#pragma unroll
    for (int f = 0; f < 4; ++f) acc[f] = (f32x4)0.f;

#define STAGE(B, CT)                                                           \
    do {                                                                       \
        _Pragma("unroll")                                                      \
        for (int q_ = 0; q_ < 4; ++q_) {                                       \
            const int cc_ = 4 * w + q_;                                        \
            const int row_ = 4 * cc_ + (l >> 4);                               \
            const int su_ = (l & 15) ^ (row_ & 7);                             \
            const float* gp_ = U +                                             \
                (size_t)(TM ? (kbase + (CT) * 64 + row_) : (x0 + row_)) * NN + \
                (TM ? x0 : (kbase + (CT) * 64)) + su_ * 4;                     \
            gload16(gp_, &tile[B][cc_ * 256]);                                 \
        }                                                                      \
    } while (0)

#define LOADFB(R, CT)                                                          \
    do {                                                                       \
        _Pragma("unroll")                                                      \
        for (int sp_ = 0; sp_ < 2; ++sp_)                                      \
            _Pragma("unroll")                                                  \
            for (int f_ = 0; f_ < 4; ++f_)                                     \
                R[sp_][f_] = *(const bf16x8*)(fbL +                            \
                    ((size_t)((kb0 + 2 * (CT) + sp_) * 4 + f_)) * 512);        \
    } while (0)

#define COMPUTE(B, FBR)                                                        \
    do {                                                                       \
        _Pragma("unroll")                                                      \
        for (int sp_ = 0; sp_ < 2; ++sp_) {                                    \
            if (!TM) {                                                         \
                const float* rp_ = &tile[B][(16 * w + lm) * 64];               \
                const int m7_ = lm & 7;                                        \
                f32x4 p0_ = *(const f32x4*)(rp_ +                              \
                    (((8 * sp_ + 2 * g) ^ m7_) << 2));                         \
                f32x4 p1_ = *(const f32x4*)(rp_ +                              \
                    (((8 * sp_ + 2 * g + 1) ^ m7_) << 2));                     \
                bf16x8 afr_;                                                   \
                _Pragma("unroll")                                              \
                for (int j_ = 0; j_ < 4; ++j_) {                               \
                    afr_[j_]     = (short)f2bf(p0_[j_]);                       \
                    afr_[4 + j_] = (short)f2bf(p1_[j_]);                       \
                }                                                              \
                _Pragma("unroll")                                              \
                for (int f_ = 0; f_ < 4; ++f_)                                 \
                    acc[f_] = __builtin_amdgcn_mfma_f32_16x16x32_bf16(         \
                        afr_, FBR[sp_][f_], acc[f_], 0, 0, 0);                 \
            } else {                                                           \
                bf16x8 bfr_;                                                   \
                _Pragma("unroll")                                              \
                for (int s_ = 0; s_ < 8; ++s_)                                 \
                    bfr_[s_] = (short)f2bf(tile[B][                            \
                        (32 * sp_ + 8 * g + s_) * 64 +                         \
                        (((4 * w + (lm >> 2)) ^ s_) << 2) + (lm & 3)]);        \
                _Pragma("unroll")                                              \
                for (int f_ = 0; f_ < 4; ++f_)                                 \
                    acc[f_] = __builtin_amdgcn_mfma_f32_16x16x32_bf16(         \
                        FBR[sp_][f_], bfr_, acc[f_], 0, 0, 0);                 \
            }                                                                  \
        }                                                                      \
    } while (0)

    bf16x8 fbA[2][4], fbB[2][4];
    // prologue order: s_0, fb_0, s_1  (fb_0 AFTER s_0, BEFORE s_1)
    STAGE(0, 0);
    LOADFB(fbA, 0);
    STAGE(1, 1);

    // steady phase: LOADFB(t+1) then STAGE(t+2); VMW(16); barrier; compute.
#define PH(CC, BC, BS, FBC, FBN)                                               \
    do {                                                                       \
        LOADFB(FBN, (CC) + 1);                                                 \
        STAGE(BS, (CC) + 2);                                                   \
        VMW(16);                                                               \
        SBAR();                                                                \
        COMPUTE(BC, FBC);                                                      \
        SBAR();                                                                \
    } while (0)

    PH(0, 0, 2, fbA, fbB);
    PH(1, 1, 0, fbB, fbA);
    PH(2, 2, 1, fbA, fbB);
    PH(3, 0, 2, fbB, fbA);
    PH(4, 1, 0, fbA, fbB);
    PH(5, 2, 1, fbB, fbA);
    PH(6, 0, 2, fbA, fbB);
    PH(7, 1, 0, fbB, fbA);
    PH(8, 2, 1, fbA, fbB);
    PH(9, 0, 2, fbB, fbA);
    PH(10, 1, 0, fbA, fbB);
    PH(11, 2, 1, fbB, fbA);
    PH(12, 0, 2, fbA, fbB);
    PH(13, 1, 0, fbB, fbA);
    // phase 14: fb_15 load, no stage; keep s_15(4)+fb_15(8)=12
    LOADFB(fbB, 15);
    VMW(12);
    SBAR();
    COMPUTE(2, fbA);
    SBAR();
    // phase 15: drain all
    VMW(0);
    SBAR();
    COMPUTE(0, fbB);
#undef PH
#undef STAGE
#undef LOADFB
#undef COMPUTE

    if (!TM) {
        unsigned short* Pp = Pout + (size_t)blockIdx.y * NN * 64;
#pragma unroll
        for (int f = 0; f < 4; ++f)
#pragma unroll
            for (int r = 0; r < 4; ++r)
                Pp[(size_t)(x0 + 16 * w + 4 * g + r) * 64 + f * 16 + lm] =
                    f2bf(acc[f][r]);
    } else {
        unsigned short* Pp = Pout + (size_t)blockIdx.y * 64 * NN;
#pragma unroll
        for (int f = 0; f < 4; ++f)
#pragma unroll
            for (int r = 0; r < 4; ++r)
                Pp[(size_t)(16 * f + 4 * g + r) * NN + x0 + 16 * w + lm] =
                    f2bf(acc[f][r]);
    }
}

// reduce2: FB = frag( colscale(V) * sum_sk Pt[sk][ch][i] ), Pt bf16 [SK][64][NN]
__global__ __launch_bounds__(256) void reduce2(const unsigned short* __restrict__ Pt,
        const float* __restrict__ V, unsigned short* __restrict__ FB) {
    int b = blockIdx.x;
    int t = threadIdx.x;
    int nf = t >> 6, l = t & 63, lm = l & 15, g = l >> 4;
    int ch = 16 * nf + lm;
    int ib = 32 * b + 8 * g;
    float s[8];
#pragma unroll
    for (int c = 0; c < 8; ++c) s[c] = 0.f;
#pragma unroll
    for (int sk = 0; sk < SK; ++sk) {
        u16x8 v = *(const u16x8*)(Pt + (size_t)(sk * 64 + ch) * NN + ib);
#pragma unroll
        for (int c = 0; c < 8; ++c) s[c] += bf2f(v[c]);
    }
    f32x4 v0 = *(const f32x4*)(V + ib);
    f32x4 v1 = *(const f32x4*)(V + ib + 4);
    u16x8 o;
#pragma unroll
    for (int c = 0; c < 4; ++c) {
        o[c]     = f2bf(s[c] * v0[c]);
        o[4 + c] = f2bf(s[4 + c] * v1[c]);
    }
    *(u16x8*)(FB + ((size_t)(b * 4 + nf) * 64 + l) * 8) = o;
}

// reduce_t<BF>: FB = frag( sum_sk M[sk][i][j] ).
//   BF=0: M f32 (the X input, nsk=1). BF=1: M bf16 partials [nsk][NN][64].
template<int BF>
__global__ __launch_bounds__(256) void reduce_t(const void* __restrict__ M, int nsk,
        unsigned short* __restrict__ FB) {
    __shared__ float T[32][65];
    int b = blockIdx.x;
    int i0 = b * 32;
    int tid = threadIdx.x;
    int il = tid >> 3, jq = (tid & 7) * 8;
    float s[8];
#pragma unroll
    for (int c = 0; c < 8; ++c) s[c] = 0.f;
    for (int k = 0; k < nsk; ++k) {
        if (!BF) {
            const float* p = (const float*)M + ((size_t)k * NN + i0 + il) * 64 + jq;
            f32x4 a = *(const f32x4*)p;
            f32x4 bq = *(const f32x4*)(p + 4);
#pragma unroll
            for (int c = 0; c < 4; ++c) { s[c] += a[c]; s[4 + c] += bq[c]; }
        } else {
            u16x8 v = *(const u16x8*)((const unsigned short*)M +
                ((size_t)k * NN + i0 + il) * 64 + jq);
#pragma unroll
            for (int c = 0; c < 8; ++c) s[c] += bf2f(v[c]);
        }
    }
#pragma unroll
    for (int c = 0; c < 8; ++c) T[il][jq + c] = s[c];
    __syncthreads();
    int nf = tid >> 6, l = tid & 63, g = l >> 4, lm = l & 15;
    u16x8 o;
#pragma unroll
    for (int q = 0; q < 8; ++q) o[q] = f2bf(T[8 * g + q][16 * nf + lm]);
    *(u16x8*)(FB + ((size_t)(b * 4 + nf) * 64 + l) * 8) = o;
}

// Z2 = sum of bf16 partials; hidden = Z2 @ Ww^T + Wb; + per-block BN sums.
__global__ __launch_bounds__(256) void reduce_linear(
        const unsigned short* __restrict__ P,
        const float* __restrict__ Ww, const float* __restrict__ Wb,
        float* __restrict__ hidden, float* __restrict__ bsum, float* __restrict__ bsq) {
    __shared__ float z[32][65];
    __shared__ float w[64][65];
    __shared__ float hl[32][65];
    int i0 = blockIdx.x * 32;
    int tid = threadIdx.x;
    for (int e = tid * 4; e < 4096; e += 1024) {
        f32x4 v = *(const f32x4*)(Ww + e);
        int h = e >> 6, c = e & 63;
#pragma unroll
        for (int q = 0; q < 4; ++q) w[h][c + q] = v[q];
    }
    int r = tid >> 3, c8 = (tid & 7) * 8;
    float s[8];
#pragma unroll
    for (int q = 0; q < 8; ++q) s[q] = 0.f;
    for (int k = 0; k < SK; ++k) {
        u16x8 v = *(const u16x8*)(P + ((size_t)k * NN + i0 + r) * 64 + c8);
#pragma unroll
        for (int q = 0; q < 8; ++q) s[q] += bf2f(v[q]);
    }
#pragma unroll
    for (int q = 0; q < 8; ++q) z[r][c8 + q] = s[q];
    __syncthreads();
    int h8 = (tid & 7) * 8;
#pragma unroll
    for (int hh = 0; hh < 8; ++hh) {
        int h = h8 + hh;
        float sv = Wb[h];
        for (int c = 0; c < 64; ++c) sv += z[r][c] * w[h][c];
        hidden[(size_t)(i0 + r) * 64 + h] = sv;
        hl[r][h] = sv;
    }
    __syncthreads();
    if (tid < 64) {
        float sv = 0.f, q2 = 0.f;
#pragma unroll
        for (int rr = 0; rr < 32; ++rr) {
            float v = hl[rr][tid];
            sv += v; q2 += v * v;
        }
        bsum[blockIdx.x * 64 + tid] = sv;
        bsq[blockIdx.x * 64 + tid] = q2;
    }
}

__global__ __launch_bounds__(64) void bn_stats(const float* __restrict__ bsum,
        const float* __restrict__ bsq, const float* __restrict__ gamma,
        const float* __restrict__ beta, float* __restrict__ bnc) {
    int h = threadIdx.x;
    float s = 0.f, q = 0.f;
    for (int b = 0; b < 256; ++b) { s += bsum[b * 64 + h]; q += bsq[b * 64 + h]; }
    float mean = s / 8192.0f;
    float var = q / 8192.0f - mean * mean;
    float inv = rsqrtf(var + 1e-5f);
    float sc = gamma[h] * inv;
    bnc[h] = sc;
    bnc[64 + h] = beta[h] - mean * sc;
}

__global__ __launch_bounds__(256) void head(const float* __restrict__ hidden,
        const float* __restrict__ bnc, const float* __restrict__ Mw,
        const float* __restrict__ Mb, float* __restrict__ out0) {
    __shared__ float a[32][65];
    __shared__ float w[32][65];
    __shared__ float o[32][33];
    __shared__ float rowm[32];
    int i0 = blockIdx.x * 32;
    int tid = threadIdx.x;
    for (int e = tid * 4; e < 2048; e += 1024) {
        f32x4 v = *(const f32x4*)(Mw + e);
        int oo = e >> 6, c = e & 63;
#pragma unroll
        for (int q = 0; q < 4; ++q) w[oo][c + q] = v[q];
    }
    int r = tid >> 3, h8 = (tid & 7) * 8;
    const float* hp = hidden + (size_t)(i0 + r) * 64 + h8;
#pragma unroll
    for (int q = 0; q < 8; ++q) {
        int h = h8 + q;
        float v = hp[q] * bnc[h] + bnc[64 + h];
        a[r][h] = fmaxf(v, 0.f);
    }
    __syncthreads();
    int o4 = (tid & 7) * 4;
#pragma unroll
    for (int q = 0; q < 4; ++q) {
        int oo = o4 + q;
        float s = Mb[oo];
        for (int c = 0; c < 64; ++c) s += a[r][c] * w[oo][c];
        o[r][oo] = s;
    }
    __syncthreads();
    if (tid < 32) {
        float m = -3.0e38f;
#pragma unroll
        for (int c = 0; c < 32; ++c) m = fmaxf(m, o[tid][c]);
        float se = 0.f;
#pragma unroll
        for (int c = 0; c < 32; ++c) se += expf(o[tid][c] - m);
        rowm[tid] = m + logf(se);
    }
    __syncthreads();
    f32x4 v;
#pragma unroll
    for (int q = 0; q < 4; ++q) v[q] = o[r][o4 + q] - rowm[r];
    *(f32x4*)(out0 + (size_t)(i0 + r) * 32 + o4) = v;
}

extern "C" void kernel_launch(void* const* d_in, const int* in_sizes, int n_in,
                              void* d_out, int out_size, void* d_ws, size_t ws_size,
                              hipStream_t stream) {
    const float* X   = (const float*)d_in[0];
    const float* La  = (const float*)d_in[1];
    const float* U   = (const float*)d_in[2];
    const float* ve  = (const float*)d_in[3];
    const float* ve2 = (const float*)d_in[4];
    const float* Ww  = (const float*)d_in[5];
    const float* Wb  = (const float*)d_in[6];
    const float* gam = (const float*)d_in[7];
    const float* bet = (const float*)d_in[8];
    const float* Mw  = (const float*)d_in[9];
    const float* Mb  = (const float*)d_in[10];
    float* out0 = (float*)d_out;
    float* hidden = (float*)d_out + (size_t)NN * 32;   // output 1 region

    char* ws = (char*)d_ws;
    float* V1   = (float*)ws;                             // 32 KB
    float* V2   = (float*)(ws + 32768);                   // 32 KB
    float* bsum = (float*)(ws + 65536);                   // 64 KB
    float* bsq  = (float*)(ws + 131072);                  // 64 KB
    float* bnc  = (float*)(ws + 196608);                  // 512 B
    unsigned short* FB = (unsigned short*)(ws + 262144);  // 1 MB frag-major bf16
    unsigned short* P  = (unsigned short*)(ws + (2u << 20));   // 8 MB bf16
    unsigned short* Pt = (unsigned short*)(ws + (12u << 20));  // 8 MB bf16

    prep_v<<<32, 256, 0, stream>>>(La, ve, ve2, V1, V2);
    // FB = frag(X)
    reduce_t<0><<<256, 256, 0, stream>>>(X, 1, FB);
    // T1^T partials = X^T @ U
    spec_pass<1><<<dim3(NN / 64, SK), 256, 0, stream>>>(U, FB, Pt);
    // FB = frag(V1 .* T1)
    reduce2<<<256, 256, 0, stream>>>(Pt, V1, FB);
    // Z1 = U @ S1
    spec_pass<0><<<dim3(NN / 64, SK), 256, 0, stream>>>(U, FB, P);
    // FB = frag(Z1)
    reduce_t<1><<<256, 256, 0, stream>>>(P, SK, FB);
    // T2^T partials = Z1^T @ U
    spec_pass<1><<<dim3(NN / 64, SK), 256, 0, stream>>>(U, FB, Pt);
    // FB = frag(V2 .* T2)
    reduce2<<<256, 256, 0, stream>>>(Pt, V2, FB);
    // Z2 = U @ S2
    spec_pass<0><<<dim3(NN / 64, SK), 256, 0, stream>>>(U, FB, P);
    // hidden = Z2 @ Ww^T + Wb  (+ BN partial stats)
    reduce_linear<<<256, 256, 0, stream>>>(P, Ww, Wb, hidden, bsum, bsq);
    bn_stats<<<1, 64, 0, stream>>>(bsum, bsq, gam, bet, bnc);
    head<<<256, 256, 0, stream>>>(hidden, bnc, Mw, Mb, out0);
}